// Round 3
// baseline (131.806 us; speedup 1.0000x reference)
//
#include <hip/hip_runtime.h>
#include <hip/hip_bf16.h>
#include <math.h>

// ---- static config ----
#define B_     8
#define CIN_   32
#define COUT_  32
#define H_     256
#define W_     256
#define K_     36
#define P_     3
#define KW_    7
#define TAPS_  49
#define EPS_   1e-5f
#define SLOPE_ 0.2f

// ws layout:
//   bytes [0 .. 100352)            kerB (ushort bf16) [2 g16][49 tap][64 lane][8]
//   bytes [102400 .. 102400+512K)  partials float2 [256 bo][256 tile]
#define PART_OFF_F  25600   // float offset of partials (float2 entries)

// Img_s: fp32, 4 planes [ci>>2][20 py][21 px (20 used + pad col)][4 ci]
#define IMG_PLANE_B   6736
#define IMG_ROW_B     336

// Xup parity-split layout (bytes), entry = 16B (8 bf16 = ci octet):
//   even-x: [2 g][37 y][19 xe]  row 304 B, octet 11248 B, base 0
//   odd-x:  [2 g][37 y][18 xo]  row 288 B, octet 10656 B, base 22496
// Total 43808 B (= 2*37*37*16, same as before).
#define E_ROW   304
#define E_OCT   11248
#define O_ROW   288
#define O_OCT   10656
#define O_BASE  22496

using short8_t  = __attribute__((ext_vector_type(8)))  short;
using f32x16_t  = __attribute__((ext_vector_type(16))) float;
using f32x4_t   = __attribute__((ext_vector_type(4)))  float;

__device__ inline ushort f32_to_bf16(float f) {
    unsigned int bits = __float_as_uint(f);
    unsigned int r = (bits + 0x7FFFu + ((bits >> 16) & 1u)) >> 16;
    return (ushort)r;
}

// ============================================================
// Kernel A: build pre-swizzled B-fragments (unchanged, validated).
// ============================================================
__global__ __launch_bounds__(256)
void build_kernel(const float* __restrict__ weight, ushort* __restrict__ kerB) {
    __shared__ float psi_s[K_];
    const int tap = blockIdx.x;
    const int ty  = tap / KW_;
    const int tx  = tap % KW_;
    const int tid = threadIdx.x;

    if (tid < K_) {
        const double dxy   = 2.0 / 512.0;
        const double rcut  = 0.015;           // RADIUS_CUTOFF / 2
        const int    nr    = 6, nphi = 7;
        const double dr    = rcut / nr;
        const double dphi  = 2.0 * M_PI / nphi;
        const double norm  = M_PI * (rcut * nr / (nr + 1)) * (rcut * nr / (nr + 1));
        const double q     = dxy * dxy;

        const double offy = (double)(ty - P_) * dxy;
        const double offx = (double)(tx - P_) * dxy;
        const double r    = sqrt(offx * offx + offy * offy);
        double phi = atan2(offy, offx);
        if (phi < 0.0) phi += 2.0 * M_PI;

        const int k = tid;
        double ir, iphi;
        if (k == 0) { ir = 0.0; iphi = 0.0; }
        else        { ir = (double)((k - 1) / nphi + 1) * dr;
                      iphi = (double)((k - 1) % nphi) * dphi; }

        double rv = 1.0 - fabs(r - ir) / dr;
        rv = rv > 0.0 ? rv : 0.0;
        if (r > rcut) rv = 0.0;

        double pv = 1.0;
        if (k > 0) {
            double da = fabs(phi - iphi);
            double dm = da < (2.0 * M_PI - da) ? da : (2.0 * M_PI - da);
            pv = 1.0 - dm / dphi;
            pv = pv > 0.0 ? pv : 0.0;
        }
        psi_s[k] = (float)(rv * pv * q / norm);
    }
    __syncthreads();

    for (int e = tid; e < 1024; e += 256) {
        const int g16  = e >> 9;
        const int lane = (e >> 3) & 63;
        const int j    = e & 7;
        const int o    = lane & 31;
        const int ci   = g16 * 16 + ((lane >> 5) & 1) * 8 + j;
        const float* w = weight + (size_t)(o * CIN_ + ci) * K_;
        float s = 0.f;
        #pragma unroll
        for (int k = 0; k < K_; ++k) s = fmaf(w[k], psi_s[k], s);
        kerB[((size_t)(g16 * 49 + tap) * 64 + lane) * 8 + j] = f32_to_bf16(s);
    }
}

// ============================================================
// Kernel B: fused upsample + implicit-GEMM conv + stats partials.
// grid = (16,16,B), block = 512 (8 waves). Tile = 16x16 pixels x 32 cout.
// r11: (1) Xup split into even/odd-x parity buffers -> stage-3 afrag
//   reads and stage-2 stores are pure 16B-lane-stride (conflict-minimal;
//   SWZ removed). (2) T14 async-stage split: g16=1 global loads issued
//   into registers before stage-3(g0), ds_write after its barrier ->
//   HBM gather latency hidden under 392 MFMAs.
// ============================================================
__global__ __launch_bounds__(512, 4)
void conv_mfma(const float* __restrict__ image,
               const ushort* __restrict__ kerB,
               float* __restrict__ out,
               float* __restrict__ partials) {
    __shared__ float  Img_s[6736];            // 26944 B (4 planes x 6736 B)
    __shared__ ushort Xup_s[2738 * 8];        // 43808 B (parity-split)
    __shared__ float  wp[8][32][2];           // per-wave stats partials

    const int tid  = threadIdx.x;
    const int lane = tid & 63;
    const int w    = tid >> 6;                // wave 0..7 = M-tile index
    const int j0 = blockIdx.x * 16;
    const int i0 = blockIdx.y * 16;
    const int b  = blockIdx.z;

    const int u0 = 2 * i0 - 3;
    const int v0 = 2 * j0 - 3;
    const int R0 = i0 - 2;                    // unclamped patch origin (rows)
    const int C0 = j0 - 2;                    // unclamped patch origin (cols)

    // A-fragment lane mapping (32x32x16): m = lane&31, k-half gs = lane>>5
    const int gs  = lane >> 5;
    const int tio = (lane & 31) >> 4;         // pixel-row parity within M-tile
    const int tj  = lane & 15;                // pixel col
    const int yb0 = 4 * w + 2 * tio;          // Xup row base for this lane

    f32x16_t acc;
    #pragma unroll
    for (int q = 0; q < 16; ++q) acc[q] = 0.f;

    char* img_bytes = (char*)Img_s;
    char* xup_bytes = (char*)Xup_s;

    // ---- stage-1 helpers (item e -> plane/pixel decomposition) ----
    const float* img0 = image + (size_t)(b * CIN_)       * (H_ * W_);
    const float* img1 = image + (size_t)(b * CIN_ + 16)  * (H_ * W_);

    auto s1_load = [&](const float* img, int e) -> f32x4_t {
        const int p  = e / 400;
        const int yx = e - p * 400;
        const int py = yx / 20, px = yx - py * 20;
        const int row = R0 + py, col = C0 + px;
        f32x4_t g = {0.f, 0.f, 0.f, 0.f};
        if ((unsigned)row < 256u && (unsigned)col < 256u) {
            const float* q = img + (size_t)p * 4 * (H_ * W_) + row * W_ + col;
            g[0] = q[0];
            g[1] = q[H_ * W_];
            g[2] = q[2 * (H_ * W_)];
            g[3] = q[3 * (H_ * W_)];
        }
        return g;
    };
    auto s1_store = [&](int e, f32x4_t g) {
        const int p  = e / 400;
        const int yx = e - p * 400;
        const int py = yx / 20, px = yx - py * 20;
        *(f32x4_t*)(img_bytes + p * IMG_PLANE_B + (py * 21 + px) * 16) = g;
    };

    // ---- stage 2: closed-form polyphase upsample, x-pair per item ----
    // align_corners 2x exact: ry = y>>1, wy = ((y&1)?510:255 - (R0+ry))/511.
    auto stage2 = [&]() {
        for (int e = tid; e < 1406; e += 512) {
            const int g   = (e >= 703) ? 1 : 0;
            const int r   = e - 703 * g;
            const int y   = r / 19;
            const int xp  = r - 19 * y;
            const int x   = 2 * xp;
            const int ry  = y >> 1;
            const float wy =
                (float)((((y & 1) ? 510 : 255)) - (R0 + ry)) * (1.0f / 511.0f);
            const int Ax = C0 + xp;
            const float wx0 = (float)(255 - Ax) * (1.0f / 511.0f);
            const float wx1 = (float)(510 - Ax) * (1.0f / 511.0f);
            const bool oky = ((unsigned)(u0 + y) < 512u);
            const bool ok0 = oky && ((unsigned)(v0 + x) < 512u);
            const bool ok1 = oky && ((unsigned)(v0 + x + 1) < 512u);

            const char* lo = img_bytes + (2 * g) * IMG_PLANE_B
                           + (ry * 21 + xp) * 16;
            const char* hi = lo + IMG_PLANE_B;
            const f32x4_t a00 = *(const f32x4_t*)(lo);
            const f32x4_t a01 = *(const f32x4_t*)(lo + 16);
            const f32x4_t a10 = *(const f32x4_t*)(lo + IMG_ROW_B);
            const f32x4_t a11 = *(const f32x4_t*)(lo + IMG_ROW_B + 16);
            const f32x4_t b00 = *(const f32x4_t*)(hi);
            const f32x4_t b01 = *(const f32x4_t*)(hi + 16);
            const f32x4_t b10 = *(const f32x4_t*)(hi + IMG_ROW_B);
            const f32x4_t b11 = *(const f32x4_t*)(hi + IMG_ROW_B + 16);

            // shared y-lerp: two columns x two plane-halves
            const f32x4_t cA0 = a00 + wy * (a10 - a00);
            const f32x4_t cA1 = a01 + wy * (a11 - a01);
            const f32x4_t cB0 = b00 + wy * (b10 - b00);
            const f32x4_t cB1 = b01 + wy * (b11 - b01);

            // even output x -> even buffer (linear in item index)
            {
                const f32x4_t va = cA0 + wx0 * (cA1 - cA0);
                const f32x4_t vb = cB0 + wx0 * (cB1 - cB0);
                __hip_bfloat162 h0 = __float22bfloat162_rn(make_float2(va[0], va[1]));
                __hip_bfloat162 h1 = __float22bfloat162_rn(make_float2(va[2], va[3]));
                __hip_bfloat162 h2 = __float22bfloat162_rn(make_float2(vb[0], vb[1]));
                __hip_bfloat162 h3 = __float22bfloat162_rn(make_float2(vb[2], vb[3]));
                union { short8_t s8; uint4 u4; } pk;
                pk.u4.x = ok0 ? *(unsigned int*)&h0 : 0u;
                pk.u4.y = ok0 ? *(unsigned int*)&h1 : 0u;
                pk.u4.z = ok0 ? *(unsigned int*)&h2 : 0u;
                pk.u4.w = ok0 ? *(unsigned int*)&h3 : 0u;
                *(short8_t*)(xup_bytes + g * E_OCT + y * E_ROW + xp * 16) = pk.s8;
            }
            // odd output x+1 -> odd buffer (xp=18 has no odd partner)
            if (xp < 18) {
                const f32x4_t va = cA0 + wx1 * (cA1 - cA0);
                const f32x4_t vb = cB0 + wx1 * (cB1 - cB0);
                __hip_bfloat162 h0 = __float22bfloat162_rn(make_float2(va[0], va[1]));
                __hip_bfloat162 h1 = __float22bfloat162_rn(make_float2(va[2], va[3]));
                __hip_bfloat162 h2 = __float22bfloat162_rn(make_float2(vb[0], vb[1]));
                __hip_bfloat162 h3 = __float22bfloat162_rn(make_float2(vb[2], vb[3]));
                union { short8_t s8; uint4 u4; } pk;
                pk.u4.x = ok1 ? *(unsigned int*)&h0 : 0u;
                pk.u4.y = ok1 ? *(unsigned int*)&h1 : 0u;
                pk.u4.z = ok1 ? *(unsigned int*)&h2 : 0u;
                pk.u4.w = ok1 ? *(unsigned int*)&h3 : 0u;
                *(short8_t*)(xup_bytes + O_BASE + g * O_OCT + y * O_ROW + xp * 16) = pk.s8;
            }
        }
    };

    // ---- stage 3: 49 taps, parity-split afrag reads (16B lane stride) ----
    const int ebase = gs * E_OCT + tj * 16;
    const int obase = O_BASE + gs * O_OCT + tj * 16;
    auto stage3 = [&](const ushort* kbp) {
        #pragma unroll
        for (int ky = 0; ky < KW_; ++ky) {
            short8_t bf[KW_];
            #pragma unroll
            for (int kx = 0; kx < KW_; ++kx)
                bf[kx] = *(const short8_t*)(kbp + (size_t)(ky * KW_ + kx) * 512);
            const int re = ebase + (yb0 + ky) * E_ROW;
            const int ro = obase + (yb0 + ky) * O_ROW;
            #pragma unroll
            for (int kx = 0; kx < KW_; ++kx) {
                const int addr = ((kx & 1) ? ro : re) + (kx >> 1) * 16;
                const short8_t afrag = *(const short8_t*)(xup_bytes + addr);
                acc = __builtin_amdgcn_mfma_f32_32x32x16_bf16(afrag, bf[kx], acc, 0, 0, 0);
            }
        }
    };

    // ======== pipelined schedule ========
    // g0 stage 1 (direct)
    s1_store(tid,        s1_load(img0, tid));
    s1_store(tid + 512,  s1_load(img0, tid + 512));
    s1_store(tid + 1024, s1_load(img0, tid + 1024));
    if (tid < 64) s1_store(tid + 1536, s1_load(img0, tid + 1536));
    __syncthreads();

    stage2();
    __syncthreads();

    // issue g1 global loads into registers (latency hides under stage 3)
    f32x4_t pf0 = s1_load(img1, tid);
    f32x4_t pf1 = s1_load(img1, tid + 512);
    f32x4_t pf2 = s1_load(img1, tid + 1024);
    f32x4_t pf3 = {0.f, 0.f, 0.f, 0.f};
    if (tid < 64) pf3 = s1_load(img1, tid + 1536);

    stage3(kerB + (size_t)lane * 8);
    __syncthreads();                 // Xup(g0) consumed; Img_s dead

    // write g1 registers to Img_s
    s1_store(tid,        pf0);
    s1_store(tid + 512,  pf1);
    s1_store(tid + 1024, pf2);
    if (tid < 64) s1_store(tid + 1536, pf3);
    __syncthreads();

    stage2();
    __syncthreads();

    stage3(kerB + (size_t)(49 * 64 + lane) * 8);

    // ---- epilogue: C-writes (layout col n=lane&31, row m=(q&3)+8*(q>>2)+4*gs)
    const int n = lane & 31;
    float* op = out + (size_t)(b * COUT_ + n) * (H_ * W_);
    const int ibase = i0 + 2 * w;
    #pragma unroll
    for (int grp = 0; grp < 4; ++grp) {
        const int ti  = ibase + (grp >> 1);
        const int tjj = j0 + ((grp & 1) ? 8 : 0) + 4 * gs;
        f32x4_t s;
        s[0] = acc[grp * 4 + 0]; s[1] = acc[grp * 4 + 1];
        s[2] = acc[grp * 4 + 2]; s[3] = acc[grp * 4 + 3];
        *(f32x4_t*)(op + (size_t)ti * W_ + tjj) = s;
    }

    // ---- epilogue: InstanceNorm partial sums from registers ----
    float s1 = 0.f, s2 = 0.f;
    #pragma unroll
    for (int q = 0; q < 16; ++q) { s1 += acc[q]; s2 = fmaf(acc[q], acc[q], s2); }
    s1 += __shfl_xor(s1, 32);
    s2 += __shfl_xor(s2, 32);
    if (lane < 32) { wp[w][lane][0] = s1; wp[w][lane][1] = s2; }
    __syncthreads();
    if (tid < 32) {
        float t1 = 0.f, t2 = 0.f;
        #pragma unroll
        for (int wv = 0; wv < 8; ++wv) { t1 += wp[wv][tid][0]; t2 += wp[wv][tid][1]; }
        const int tile = blockIdx.y * 16 + blockIdx.x;
        float2* pp = (float2*)partials;
        pp[((b * 32 + tid) << 8) | tile] = make_float2(t1, t2);
    }
}

// ============================================================
// Kernel C: per-block stats reduce + normalize + LeakyReLU.
// ============================================================
__global__ __launch_bounds__(256)
void norm2_kernel(float* __restrict__ y, const float* __restrict__ partials) {
    __shared__ float r1[256];
    __shared__ float r2[256];
    const int tid = threadIdx.x;
    const int blk = blockIdx.x;
    const int bo  = blk >> 6;                  // 64 blocks per channel
    const float2 p = ((const float2*)partials)[(bo << 8) | tid];
    r1[tid] = p.x; r2[tid] = p.y;
    __syncthreads();
    for (int off = 128; off > 0; off >>= 1) {
        if (tid < off) { r1[tid] += r1[tid + off]; r2[tid] += r2[tid + off]; }
        __syncthreads();
    }
    const float inv = 1.0f / 65536.0f;
    const float m   = r1[0] * inv;
    const float var = r2[0] * inv - m * m;
    const float rs  = 1.0f / sqrtf(var + EPS_);

    const int e = blk * 256 + tid;             // float4 index
    float4 v = ((const float4*)y)[e];
    v.x = (v.x - m) * rs; v.x = v.x >= 0.f ? v.x : SLOPE_ * v.x;
    v.y = (v.y - m) * rs; v.y = v.y >= 0.f ? v.y : SLOPE_ * v.y;
    v.z = (v.z - m) * rs; v.z = v.z >= 0.f ? v.z : SLOPE_ * v.z;
    v.w = (v.w - m) * rs; v.w = v.w >= 0.f ? v.w : SLOPE_ * v.w;
    ((float4*)y)[e] = v;
}

// ============================================================
extern "C" void kernel_launch(void* const* d_in, const int* in_sizes, int n_in,
                              void* d_out, int out_size, void* d_ws, size_t ws_size,
                              hipStream_t stream) {
    const float* image  = (const float*)d_in[0];
    const float* weight = (const float*)d_in[1];
    float*  out      = (float*)d_out;
    ushort* kerB     = (ushort*)d_ws;
    float*  partials = (float*)d_ws + PART_OFF_F;

    build_kernel<<<dim3(TAPS_), dim3(256), 0, stream>>>(weight, kerB);
    conv_mfma<<<dim3(16, 16, B_), dim3(512), 0, stream>>>(image, kerB, out, partials);
    norm2_kernel<<<dim3(16384), dim3(256), 0, stream>>>(out, partials);
}

// Round 4
// 126.716 us; speedup vs baseline: 1.0402x; 1.0402x over previous
//
#include <hip/hip_runtime.h>
#include <hip/hip_bf16.h>
#include <math.h>

// ---- static config ----
#define B_     8
#define CIN_   32
#define COUT_  32
#define H_     256
#define W_     256
#define K_     36
#define P_     3
#define KW_    7
#define TAPS_  49
#define EPS_   1e-5f
#define SLOPE_ 0.2f

// ws layout:
//   bytes [0 .. 114688)          kerB bf16 frags [4 oct][7 ky][4 pair][64 lane][8]
//   bytes [114688 .. +512K)      partials float2 [256 bo][256 tile]
#define PART_OFF_F  28672   // float offset of partials

// Img_s: fp32, 2 planes [ci-quad][20 py][21 px][4 ci], plane 6736 B
#define IMG_PLANE_B   6736
#define IMG_ROW_B     336

// Xup: ONE ci-octet per pass, parity-split:
//   even-x: 37 rows x 19 entries (x=0,2,..,36)        base 0
//   odd-x:  37 rows x 19 entries (x=1,..,35, pad@18)  base 11248
// entry = 16 B (8 bf16 ci octet). row stride 304 B. total 22496 B.
#define XP_ROW   304
#define XO_BASE  11248

using short8_t  = __attribute__((ext_vector_type(8)))  short;
using f32x16_t  = __attribute__((ext_vector_type(16))) float;
using f32x4_t   = __attribute__((ext_vector_type(4)))  float;

__device__ inline ushort f32_to_bf16(float f) {
    unsigned int bits = __float_as_uint(f);
    unsigned int r = (bits + 0x7FFFu + ((bits >> 16) & 1u)) >> 16;
    return (ushort)r;
}

// ============================================================
// Kernel A: build B-fragments in tap-pair packing.
// grid = 112 (= 4 oct x 7 ky x 4 pair). Frag lane (n=lane&31, gs=lane>>5),
// j=0..7: value = dense_kernel[n][oct*8+j][tap ky*7 + 2p+gs], 0 if 2p+gs>6.
// ============================================================
__global__ __launch_bounds__(256)
void build_kernel(const float* __restrict__ weight, ushort* __restrict__ kerB) {
    __shared__ float psi_s[2][K_];            // psi for taps 2p, 2p+1 of row ky
    const int f  = blockIdx.x;
    const int p  = f & 3;
    const int ky = (f >> 2) % 7;
    const int oc = f / 28;
    const int tid = threadIdx.x;

    if (tid < 2 * K_) {
        const int tt = tid / K_;              // which tap of the pair
        const int k  = tid - tt * K_;
        const int kx = 2 * p + tt;
        float val = 0.f;
        if (kx <= 6) {
            const double dxy   = 2.0 / 512.0;
            const double rcut  = 0.015;       // RADIUS_CUTOFF / 2
            const int    nr    = 6, nphi = 7;
            const double dr    = rcut / nr;
            const double dphi  = 2.0 * M_PI / nphi;
            const double norm  = M_PI * (rcut * nr / (nr + 1)) * (rcut * nr / (nr + 1));
            const double q     = dxy * dxy;
            const double offy = (double)(ky - P_) * dxy;
            const double offx = (double)(kx - P_) * dxy;
            const double r    = sqrt(offx * offx + offy * offy);
            double phi = atan2(offy, offx);
            if (phi < 0.0) phi += 2.0 * M_PI;
            double ir, iphi;
            if (k == 0) { ir = 0.0; iphi = 0.0; }
            else        { ir = (double)((k - 1) / nphi + 1) * dr;
                          iphi = (double)((k - 1) % nphi) * dphi; }
            double rv = 1.0 - fabs(r - ir) / dr;
            rv = rv > 0.0 ? rv : 0.0;
            if (r > rcut) rv = 0.0;
            double pv = 1.0;
            if (k > 0) {
                double da = fabs(phi - iphi);
                double dm = da < (2.0 * M_PI - da) ? da : (2.0 * M_PI - da);
                pv = 1.0 - dm / dphi;
                pv = pv > 0.0 ? pv : 0.0;
            }
            val = (float)(rv * pv * q / norm);
        }
        psi_s[tt][k] = val;
    }
    __syncthreads();

    // 512 outputs per frag, 2 per thread
    for (int e = tid; e < 512; e += 256) {
        const int lane = e >> 3;
        const int j    = e & 7;
        const int gs   = lane >> 5;
        const int n    = lane & 31;
        const int kx   = 2 * p + gs;
        float s = 0.f;
        if (kx <= 6) {
            const int ci = oc * 8 + j;
            const float* w = weight + (size_t)(n * CIN_ + ci) * K_;
            #pragma unroll
            for (int k = 0; k < K_; ++k) s = fmaf(w[k], psi_s[gs][k], s);
        }
        kerB[((size_t)f * 64 + lane) * 8 + j] = f32_to_bf16(s);
    }
}

// ============================================================
// Kernel B: fused upsample + implicit-GEMM conv + stats partials.
// grid = (16,16,B), block = 512 (8 waves). Tile = 16x16 pixels x 32 cout.
// r12: K repacked as (2 adjacent taps) x (8 ci) -> one ci-octet resident
// per pass. 4 passes over ci octets. LDS 73.2K -> 38K => 4 blocks/CU,
// 32/32 waves (launch_bounds(512,8)). Per-pass: stage1 (2 planes),
// stage2 (closed-form polyphase x-pair), stage3 (7 ky x 4 pair MFMAs;
// gs half reads even/odd parity buffer at entry tj+p).
// ============================================================
__global__ __launch_bounds__(512, 8)
void conv_mfma(const float* __restrict__ image,
               const ushort* __restrict__ kerB,
               float* __restrict__ out,
               float* __restrict__ partials) {
    __shared__ float  Img_s[3368];            // 13472 B (2 planes x 6736 B)
    __shared__ ushort Xup_s[11248];           // 22496 B (parity-split, 1 octet)
    __shared__ float  wp[8][32][2];           // per-wave stats partials

    const int tid  = threadIdx.x;
    const int lane = tid & 63;
    const int w    = tid >> 6;                // wave 0..7 = M-tile index
    const int j0 = blockIdx.x * 16;
    const int i0 = blockIdx.y * 16;
    const int b  = blockIdx.z;

    const int u0 = 2 * i0 - 3;
    const int v0 = 2 * j0 - 3;
    const int R0 = i0 - 2;                    // unclamped patch origin (rows)
    const int C0 = j0 - 2;                    // unclamped patch origin (cols)

    // A-fragment lane mapping (32x32x16): m = lane&31, k-half gs = lane>>5
    const int gs  = lane >> 5;                // which tap of the pair
    const int tio = (lane & 31) >> 4;
    const int tj  = lane & 15;
    const int yb0 = 4 * w + 2 * tio;

    f32x16_t acc;
    #pragma unroll
    for (int q = 0; q < 16; ++q) acc[q] = 0.f;

    char* img_bytes = (char*)Img_s;
    char* xup_bytes = (char*)Xup_s;

    const float* imgb = image + (size_t)(b * CIN_) * (H_ * W_);

    for (int oc = 0; oc < 4; ++oc) {
        // ---- stage 1: 20x20 patch, 2 ci-quad planes of this octet ----
        const float* img = imgb + (size_t)(oc * 8) * (H_ * W_);
        for (int e = tid; e < 800; e += 512) {
            const int p  = (e >= 400) ? 1 : 0;       // ci quad within octet
            const int yx = e - p * 400;
            const int py = yx / 20, px = yx - py * 20;
            const int row = R0 + py, col = C0 + px;
            f32x4_t g = {0.f, 0.f, 0.f, 0.f};
            if ((unsigned)row < 256u && (unsigned)col < 256u) {
                const float* q = img + (size_t)p * 4 * (H_ * W_) + row * W_ + col;
                g[0] = q[0];
                g[1] = q[H_ * W_];
                g[2] = q[2 * (H_ * W_)];
                g[3] = q[3 * (H_ * W_)];
            }
            *(f32x4_t*)(img_bytes + p * IMG_PLANE_B + (py * 21 + px) * 16) = g;
        }
        __syncthreads();

        // ---- stage 2: closed-form polyphase upsample, x-pair per item ----
        // ry = y>>1, wy = ((y&1)?510:255 - (R0+ry))/511 (align_corners 2x).
        for (int e = tid; e < 703; e += 512) {
            const int y   = e / 19;
            const int xp  = e - 19 * y;
            const int x   = 2 * xp;
            const int ry  = y >> 1;
            const float wy =
                (float)((((y & 1) ? 510 : 255)) - (R0 + ry)) * (1.0f / 511.0f);
            const int Ax = C0 + xp;
            const float wx0 = (float)(255 - Ax) * (1.0f / 511.0f);
            const float wx1 = (float)(510 - Ax) * (1.0f / 511.0f);
            const bool oky = ((unsigned)(u0 + y) < 512u);
            const bool ok0 = oky && ((unsigned)(v0 + x) < 512u);
            const bool ok1 = oky && ((unsigned)(v0 + x + 1) < 512u) && (xp < 18);

            const char* lo = img_bytes + (ry * 21 + xp) * 16;
            const char* hi = lo + IMG_PLANE_B;
            const f32x4_t a00 = *(const f32x4_t*)(lo);
            const f32x4_t a01 = *(const f32x4_t*)(lo + 16);
            const f32x4_t a10 = *(const f32x4_t*)(lo + IMG_ROW_B);
            const f32x4_t a11 = *(const f32x4_t*)(lo + IMG_ROW_B + 16);
            const f32x4_t b00 = *(const f32x4_t*)(hi);
            const f32x4_t b01 = *(const f32x4_t*)(hi + 16);
            const f32x4_t b10 = *(const f32x4_t*)(hi + IMG_ROW_B);
            const f32x4_t b11 = *(const f32x4_t*)(hi + IMG_ROW_B + 16);

            const f32x4_t cA0 = a00 + wy * (a10 - a00);
            const f32x4_t cA1 = a01 + wy * (a11 - a01);
            const f32x4_t cB0 = b00 + wy * (b10 - b00);
            const f32x4_t cB1 = b01 + wy * (b11 - b01);

            // even output -> even buffer (linear store)
            {
                const f32x4_t va = cA0 + wx0 * (cA1 - cA0);
                const f32x4_t vb = cB0 + wx0 * (cB1 - cB0);
                __hip_bfloat162 h0 = __float22bfloat162_rn(make_float2(va[0], va[1]));
                __hip_bfloat162 h1 = __float22bfloat162_rn(make_float2(va[2], va[3]));
                __hip_bfloat162 h2 = __float22bfloat162_rn(make_float2(vb[0], vb[1]));
                __hip_bfloat162 h3 = __float22bfloat162_rn(make_float2(vb[2], vb[3]));
                union { short8_t s8; uint4 u4; } pk;
                pk.u4.x = ok0 ? *(unsigned int*)&h0 : 0u;
                pk.u4.y = ok0 ? *(unsigned int*)&h1 : 0u;
                pk.u4.z = ok0 ? *(unsigned int*)&h2 : 0u;
                pk.u4.w = ok0 ? *(unsigned int*)&h3 : 0u;
                *(short8_t*)(xup_bytes + y * XP_ROW + xp * 16) = pk.s8;
            }
            // odd output -> odd buffer; xp==18 writes the zero pad entry
            {
                const f32x4_t va = cA0 + wx1 * (cA1 - cA0);
                const f32x4_t vb = cB0 + wx1 * (cB1 - cB0);
                __hip_bfloat162 h0 = __float22bfloat162_rn(make_float2(va[0], va[1]));
                __hip_bfloat162 h1 = __float22bfloat162_rn(make_float2(va[2], va[3]));
                __hip_bfloat162 h2 = __float22bfloat162_rn(make_float2(vb[0], vb[1]));
                __hip_bfloat162 h3 = __float22bfloat162_rn(make_float2(vb[2], vb[3]));
                union { short8_t s8; uint4 u4; } pk;
                pk.u4.x = ok1 ? *(unsigned int*)&h0 : 0u;
                pk.u4.y = ok1 ? *(unsigned int*)&h1 : 0u;
                pk.u4.z = ok1 ? *(unsigned int*)&h2 : 0u;
                pk.u4.w = ok1 ? *(unsigned int*)&h3 : 0u;
                *(short8_t*)(xup_bytes + XO_BASE + y * XP_ROW + xp * 16) = pk.s8;
            }
        }
        __syncthreads();

        // ---- stage 3: 7 ky x 4 tap-pair MFMAs ----
        // gs half reads parity buffer gs at entry (tj + p), row yb0+ky.
        const int pbase = (gs ? XO_BASE : 0) + tj * 16;
        const ushort* kbp = kerB + ((size_t)(oc * 28) * 64 + lane) * 8;
        #pragma unroll
        for (int ky = 0; ky < KW_; ++ky) {
            short8_t bf[4];
            #pragma unroll
            for (int p = 0; p < 4; ++p)
                bf[p] = *(const short8_t*)(kbp + (size_t)(ky * 4 + p) * 512);
            const int rbase = pbase + (yb0 + ky) * XP_ROW;
            #pragma unroll
            for (int p = 0; p < 4; ++p) {
                const short8_t afrag = *(const short8_t*)(xup_bytes + rbase + p * 16);
                acc = __builtin_amdgcn_mfma_f32_32x32x16_bf16(afrag, bf[p], acc, 0, 0, 0);
            }
        }
        __syncthreads();   // before next pass's staging overwrites LDS
    }

    // ---- epilogue: C-writes (layout col n=lane&31, row m=(q&3)+8*(q>>2)+4*gs)
    const int n = lane & 31;
    float* op = out + (size_t)(b * COUT_ + n) * (H_ * W_);
    const int ibase = i0 + 2 * w;
    #pragma unroll
    for (int grp = 0; grp < 4; ++grp) {
        const int ti  = ibase + (grp >> 1);
        const int tjj = j0 + ((grp & 1) ? 8 : 0) + 4 * gs;
        f32x4_t s;
        s[0] = acc[grp * 4 + 0]; s[1] = acc[grp * 4 + 1];
        s[2] = acc[grp * 4 + 2]; s[3] = acc[grp * 4 + 3];
        *(f32x4_t*)(op + (size_t)ti * W_ + tjj) = s;
    }

    // ---- epilogue: InstanceNorm partial sums from registers ----
    float s1 = 0.f, s2 = 0.f;
    #pragma unroll
    for (int q = 0; q < 16; ++q) { s1 += acc[q]; s2 = fmaf(acc[q], acc[q], s2); }
    s1 += __shfl_xor(s1, 32);
    s2 += __shfl_xor(s2, 32);
    if (lane < 32) { wp[w][lane][0] = s1; wp[w][lane][1] = s2; }
    __syncthreads();
    if (tid < 32) {
        float t1 = 0.f, t2 = 0.f;
        #pragma unroll
        for (int wv = 0; wv < 8; ++wv) { t1 += wp[wv][tid][0]; t2 += wp[wv][tid][1]; }
        const int tile = blockIdx.y * 16 + blockIdx.x;
        float2* pp = (float2*)partials;
        pp[((b * 32 + tid) << 8) | tile] = make_float2(t1, t2);
    }
}

// ============================================================
// Kernel C: per-block stats reduce + normalize + LeakyReLU.
// ============================================================
__global__ __launch_bounds__(256)
void norm2_kernel(float* __restrict__ y, const float* __restrict__ partials) {
    __shared__ float r1[256];
    __shared__ float r2[256];
    const int tid = threadIdx.x;
    const int blk = blockIdx.x;
    const int bo  = blk >> 6;                  // 64 blocks per channel
    const float2 p = ((const float2*)partials)[(bo << 8) | tid];
    r1[tid] = p.x; r2[tid] = p.y;
    __syncthreads();
    for (int off = 128; off > 0; off >>= 1) {
        if (tid < off) { r1[tid] += r1[tid + off]; r2[tid] += r2[tid + off]; }
        __syncthreads();
    }
    const float inv = 1.0f / 65536.0f;
    const float m   = r1[0] * inv;
    const float var = r2[0] * inv - m * m;
    const float rs  = 1.0f / sqrtf(var + EPS_);

    const int e = blk * 256 + tid;             // float4 index
    float4 v = ((const float4*)y)[e];
    v.x = (v.x - m) * rs; v.x = v.x >= 0.f ? v.x : SLOPE_ * v.x;
    v.y = (v.y - m) * rs; v.y = v.y >= 0.f ? v.y : SLOPE_ * v.y;
    v.z = (v.z - m) * rs; v.z = v.z >= 0.f ? v.z : SLOPE_ * v.z;
    v.w = (v.w - m) * rs; v.w = v.w >= 0.f ? v.w : SLOPE_ * v.w;
    ((float4*)y)[e] = v;
}

// ============================================================
extern "C" void kernel_launch(void* const* d_in, const int* in_sizes, int n_in,
                              void* d_out, int out_size, void* d_ws, size_t ws_size,
                              hipStream_t stream) {
    const float* image  = (const float*)d_in[0];
    const float* weight = (const float*)d_in[1];
    float*  out      = (float*)d_out;
    ushort* kerB     = (ushort*)d_ws;
    float*  partials = (float*)d_ws + PART_OFF_F;

    build_kernel<<<dim3(112), dim3(256), 0, stream>>>(weight, kerB);
    conv_mfma<<<dim3(16, 16, B_), dim3(512), 0, stream>>>(image, kerB, out, partials);
    norm2_kernel<<<dim3(16384), dim3(256), 0, stream>>>(out, partials);
}